// Round 1
// baseline (96.555 us; speedup 1.0000x reference)
//
#include <hip/hip_runtime.h>
#include <hip/hip_bf16.h>

typedef __attribute__((ext_vector_type(8))) short short8;
typedef __attribute__((ext_vector_type(4))) float f32x4;

#define HWPIX 147456   // 384*384
#define NC 64
#define NO 64
#define NM 4
#define EPSV 1e-5f

__device__ __forceinline__ unsigned short f2bf(float f) {
    unsigned int u = __float_as_uint(f);
    u += 0x7fffu + ((u >> 16) & 1u);          // round-to-nearest-even
    return (unsigned short)(u >> 16);
}
__device__ __forceinline__ float bf2f(unsigned short h) {
    return __uint_as_float(((unsigned int)h) << 16);
}

// Fused: LayerNorm(C) -> stacked 1x1 conv (256x64 matvec, split-bf16 MFMA)
// -> sum_m relu(z - q).  A = W (regs), B = xn^T (LDS, XOR-swizzled).
__global__ __launch_bounds__(256) void dnm_fused(
    const float* __restrict__ x, const float* __restrict__ Wg,
    const float* __restrict__ qp, const float* __restrict__ gamma,
    const float* __restrict__ beta, float* __restrict__ out)
{
    // xn hi at [0,8K), lo at [8K,16K).  Row = pixel (64 rows x 128B), 16B slots
    // swizzled: byte = r*128 + ((slot ^ (r&7))<<4)
    __shared__ __align__(16) unsigned char lds[16384];

    const int tid = threadIdx.x;
    const int wv  = tid >> 6;        // wave 0..3  (owns o-slice wv*16..+16)
    const int ln  = tid & 63;
    const int p16 = ln & 15;         // pixel-local / A-row-local
    const int g4  = ln >> 4;         // lane group 0..3 (k-chunk group)

    const int bid = blockIdx.x;      // 2304 blocks: 576 per batch image
    const int b       = bid / 576;
    const int pixbase = (bid % 576) * 256;

    const float qv = qp[0];

    // ---- W fragments (A operand), loaded once per block into registers.
    // ntile (m, wv): A row o = wv*16 + p16 ; k = ch*32 + g4*8 + j
    short8 wh[NM][2], wl[NM][2];
#pragma unroll
    for (int m = 0; m < NM; ++m) {
#pragma unroll
        for (int ch = 0; ch < 2; ++ch) {
            const float* wp = Wg + ((m * NO + (wv * 16 + p16)) * NC + ch * 32 + g4 * 8);
            f32x4 a = *(const f32x4*)(wp);
            f32x4 c = *(const f32x4*)(wp + 4);
            float f[8] = {a[0], a[1], a[2], a[3], c[0], c[1], c[2], c[3]};
#pragma unroll
            for (int j = 0; j < 8; ++j) {
                unsigned short h  = f2bf(f[j]);
                unsigned short lo = f2bf(f[j] - bf2f(h));
                wh[m][ch][j] = (short)h;
                wl[m][ch][j] = (short)lo;
            }
        }
    }

    const size_t outbase = (size_t)b * NO * HWPIX;
    const float* xb = x + (size_t)b * NC * HWPIX;

#pragma unroll 1
    for (int it = 0; it < 4; ++it) {
        const int tilebase = pixbase + it * 64;

        // ---- LayerNorm: this wave handles pixel-subtile `wv` (16 pixels),
        // 4 lanes per pixel, 16 channels per lane.
        {
            const int gp = tilebase + wv * 16 + p16;
            const float* xp = xb + gp;
            float xv[16];
            float s1 = 0.f, s2 = 0.f;
#pragma unroll
            for (int i = 0; i < 16; ++i) {
                float v = xp[(size_t)(g4 * 16 + i) * HWPIX];
                xv[i] = v;
                s1 += v;
                s2 += v * v;
            }
            s1 += __shfl_xor(s1, 16);  s2 += __shfl_xor(s2, 16);
            s1 += __shfl_xor(s1, 32);  s2 += __shfl_xor(s2, 32);
            const float mu  = s1 * (1.f / 64.f);
            const float var = s2 * (1.f / 64.f) - mu * mu;   // biased, matches torch
            const float rs  = rsqrtf(var + EPSV);

            const int r  = wv * 16 + p16;
            const int rk = r & 7;
            short8 hi0, hi1, lo0, lo1;
#pragma unroll
            for (int i = 0; i < 16; ++i) {
                const int c = g4 * 16 + i;
                float xn = (xv[i] - mu) * rs * gamma[c] + beta[c];
                unsigned short h  = f2bf(xn);
                unsigned short l2 = f2bf(xn - bf2f(h));
                if (i < 8) { hi0[i] = (short)h;     lo0[i] = (short)l2; }
                else       { hi1[i - 8] = (short)h; lo1[i - 8] = (short)l2; }
            }
            const int s0 = g4 * 2;
            *(short8*)(lds +        r * 128 + (((s0    ) ^ rk) << 4)) = hi0;
            *(short8*)(lds +        r * 128 + (((s0 + 1) ^ rk) << 4)) = hi1;
            *(short8*)(lds + 8192 + r * 128 + (((s0    ) ^ rk) << 4)) = lo0;
            *(short8*)(lds + 8192 + r * 128 + (((s0 + 1) ^ rk) << 4)) = lo1;
        }
        __syncthreads();

        // ---- MFMA: each wave covers its o-slice for all 4 pixel-subtiles.
#pragma unroll 1
        for (int ps = 0; ps < 4; ++ps) {
            const int r  = ps * 16 + p16;
            const int rk = r & 7;
            short8 bh[2], bl[2];
#pragma unroll
            for (int ch = 0; ch < 2; ++ch) {
                const int slot = ch * 4 + g4;
                bh[ch] = *(const short8*)(lds +        r * 128 + ((slot ^ rk) << 4));
                bl[ch] = *(const short8*)(lds + 8192 + r * 128 + ((slot ^ rk) << 4));
            }
            f32x4 acc[NM];
#pragma unroll
            for (int m = 0; m < NM; ++m) {
                f32x4 a = {0.f, 0.f, 0.f, 0.f};
#pragma unroll
                for (int ch = 0; ch < 2; ++ch) {
                    // split-precision: hi*hi + hi*lo + lo*hi (lo*lo dropped, ~2e-5)
                    a = __builtin_amdgcn_mfma_f32_16x16x32_bf16(wh[m][ch], bh[ch], a, 0, 0, 0);
                    a = __builtin_amdgcn_mfma_f32_16x16x32_bf16(wh[m][ch], bl[ch], a, 0, 0, 0);
                    a = __builtin_amdgcn_mfma_f32_16x16x32_bf16(wl[m][ch], bh[ch], a, 0, 0, 0);
                }
                acc[m] = a;
            }
            // fold over m: out[o] = sum_m relu(z[m,o] - q); D: col=p16, row=g4*4+rr
            const int pix = tilebase + ps * 16 + p16;
#pragma unroll
            for (int rr = 0; rr < 4; ++rr) {
                const int o = wv * 16 + g4 * 4 + rr;
                float v = fmaxf(acc[0][rr] - qv, 0.f) + fmaxf(acc[1][rr] - qv, 0.f)
                        + fmaxf(acc[2][rr] - qv, 0.f) + fmaxf(acc[3][rr] - qv, 0.f);
                out[outbase + (size_t)o * HWPIX + pix] = v;
            }
        }
        __syncthreads();   // LDS reused next iteration
    }
}

extern "C" void kernel_launch(void* const* d_in, const int* in_sizes, int n_in,
                              void* d_out, int out_size, void* d_ws, size_t ws_size,
                              hipStream_t stream) {
    const float* x     = (const float*)d_in[0];
    const float* Wg    = (const float*)d_in[1];
    const float* q     = (const float*)d_in[2];
    const float* gamma = (const float*)d_in[3];
    const float* beta  = (const float*)d_in[4];
    float* out = (float*)d_out;

    // 4 batches * 576 tiles of 256 pixels = 2304 blocks
    dnm_fused<<<dim3(2304), dim3(256), 0, stream>>>(x, Wg, q, gamma, beta, out);
}

// Round 2
// 93.793 us; speedup vs baseline: 1.0294x; 1.0294x over previous
//
#include <hip/hip_runtime.h>
#include <hip/hip_bf16.h>

typedef __attribute__((ext_vector_type(8))) short short8;
typedef __attribute__((ext_vector_type(4))) float f32x4;

#define HWPIX 147456   // 384*384
#define NC 64
#define NO 64
#define NM 4
#define EPSV 1e-5f

static __device__ __forceinline__ unsigned short f2bf(float f) {
    unsigned int u = __float_as_uint(f);
    u += 0x7fffu + ((u >> 16) & 1u);          // round-to-nearest-even
    return (unsigned short)(u >> 16);
}
static __device__ __forceinline__ float bf2f(unsigned short h) {
    return __uint_as_float(((unsigned int)h) << 16);
}

// raw barrier: LDS-visibility only, keeps global loads/stores in flight (T4)
#define BAR() do { asm volatile("s_waitcnt lgkmcnt(0)" ::: "memory"); \
                   __builtin_amdgcn_s_barrier();                      \
                   asm volatile("" ::: "memory"); } while (0)

// Fused: LayerNorm(C) -> stacked 1x1 conv (256x64 matvec, split-bf16 MFMA)
// -> sum_m relu(z - q).
// A = xn (pixels x ch, LDS double-buffered, XOR-swizzled), B = gamma*W (regs),
// beta folded into accumulator init. D[pixel][o] -> float4 stores.
__global__ __launch_bounds__(256) void dnm_fused(
    const float* __restrict__ x, const float* __restrict__ Wg,
    const float* __restrict__ qp, const float* __restrict__ gamma,
    const float* __restrict__ beta, float* __restrict__ out)
{
    // per buffer: xn hi at [0,8K), lo at [8K,16K). Row = pixel (64 x 128B),
    // 16B slots swizzled: byte = r*128 + ((slot ^ (r&7))<<4)
    __shared__ __align__(16) unsigned char lds[2][16384];

    const int tid = threadIdx.x;
    const int wv  = tid >> 6;        // wave 0..3 (owns o-slice wv*16..+16)
    const int ln  = tid & 63;
    const int p16 = ln & 15;
    const int g4  = ln >> 4;         // k-chunk group 0..3

    const int bid = blockIdx.x;      // 2304 blocks: 576 per batch image
    const int b       = bid / 576;
    const int pixbase = (bid % 576) * 256;

    const float qv = qp[0];

    // ---- B operand: W' = gamma .* W, split hi/lo; bias[m] = sum_c beta_c*W[m][o][c]
    // lane holds row o = wv*16+p16, k = ch*32 + g4*8 + j
    f32x4 gA[2], gB[2], bA[2], bB[2];
#pragma unroll
    for (int ch = 0; ch < 2; ++ch) {
        gA[ch] = *(const f32x4*)(gamma + ch * 32 + g4 * 8);
        gB[ch] = *(const f32x4*)(gamma + ch * 32 + g4 * 8 + 4);
        bA[ch] = *(const f32x4*)(beta  + ch * 32 + g4 * 8);
        bB[ch] = *(const f32x4*)(beta  + ch * 32 + g4 * 8 + 4);
    }
    short8 wh[NM][2], wl[NM][2];
    float bias[NM];
#pragma unroll
    for (int m = 0; m < NM; ++m) {
        float bsum = 0.f;
#pragma unroll
        for (int ch = 0; ch < 2; ++ch) {
            const float* wp = Wg + ((m * NO + (wv * 16 + p16)) * NC + ch * 32 + g4 * 8);
            f32x4 a = *(const f32x4*)(wp);
            f32x4 c = *(const f32x4*)(wp + 4);
            float f[8]  = {a[0], a[1], a[2], a[3], c[0], c[1], c[2], c[3]};
            float gg[8] = {gA[ch][0], gA[ch][1], gA[ch][2], gA[ch][3],
                           gB[ch][0], gB[ch][1], gB[ch][2], gB[ch][3]};
            float bb[8] = {bA[ch][0], bA[ch][1], bA[ch][2], bA[ch][3],
                           bB[ch][0], bB[ch][1], bB[ch][2], bB[ch][3]};
#pragma unroll
            for (int j = 0; j < 8; ++j) {
                bsum += bb[j] * f[j];
                float wq = gg[j] * f[j];
                unsigned short h  = f2bf(wq);
                unsigned short lo = f2bf(wq - bf2f(h));
                wh[m][ch][j] = (short)h;
                wl[m][ch][j] = (short)lo;
            }
        }
        bsum += __shfl_xor(bsum, 16);
        bsum += __shfl_xor(bsum, 32);   // full sum over c for this o
        bias[m] = bsum;
    }

    const size_t outbase = (size_t)b * NO * HWPIX;
    const float* xb  = x + (size_t)b * NC * HWPIX;
    // LN: this wave covers pixel-subtile wv; 4 lanes/pixel, 16 ch/lane
    const float* xpl = xb + pixbase + wv * 16 + p16 + (size_t)(g4 * 16) * HWPIX;
    float* const outw = out + outbase + (size_t)(wv * 16 + p16) * HWPIX + pixbase;

    // prologue: loads for it=0
    float xv[16];
#pragma unroll
    for (int i = 0; i < 16; ++i) xv[i] = xpl[(size_t)i * HWPIX];

#pragma unroll 1
    for (int it = 0; it < 4; ++it) {
        unsigned char* buf = lds[it & 1];

        // ---- LN math on prefetched xv, write bf16 hi/lo to LDS
        {
            float s1 = 0.f, s2 = 0.f;
#pragma unroll
            for (int i = 0; i < 16; ++i) { s1 += xv[i]; s2 += xv[i] * xv[i]; }
            s1 += __shfl_xor(s1, 16);  s2 += __shfl_xor(s2, 16);
            s1 += __shfl_xor(s1, 32);  s2 += __shfl_xor(s2, 32);
            const float mu  = s1 * (1.f / 64.f);
            const float var = s2 * (1.f / 64.f) - mu * mu;   // biased (torch)
            const float rs  = rsqrtf(var + EPSV);

            const int r  = wv * 16 + p16;
            const int rk = r & 7;
            short8 hi0, hi1, lo0, lo1;
#pragma unroll
            for (int i = 0; i < 16; ++i) {
                float xn = (xv[i] - mu) * rs;       // gamma/beta folded into W/bias
                unsigned short h  = f2bf(xn);
                unsigned short l2 = f2bf(xn - bf2f(h));
                if (i < 8) { hi0[i] = (short)h;     lo0[i] = (short)l2; }
                else       { hi1[i - 8] = (short)h; lo1[i - 8] = (short)l2; }
            }
            const int s0 = g4 * 2;
            *(short8*)(buf +        r * 128 + (((s0    ) ^ rk) << 4)) = hi0;
            *(short8*)(buf +        r * 128 + (((s0 + 1) ^ rk) << 4)) = hi1;
            *(short8*)(buf + 8192 + r * 128 + (((s0    ) ^ rk) << 4)) = lo0;
            *(short8*)(buf + 8192 + r * 128 + (((s0 + 1) ^ rk) << 4)) = lo1;
        }
        BAR();

        // ---- prefetch next tile's x (in flight across the MFMA phase)
        if (it < 3) {
            const float* xp = xpl + (it + 1) * 64;
#pragma unroll
            for (int i = 0; i < 16; ++i) xv[i] = xp[(size_t)i * HWPIX];
        }

        // ---- MFMA: wave covers its o-slice for all 4 pixel-subtiles
#pragma unroll 1
        for (int ps = 0; ps < 4; ++ps) {
            const int r  = ps * 16 + p16;
            const int rk = r & 7;
            short8 ah[2], al[2];
#pragma unroll
            for (int ch = 0; ch < 2; ++ch) {
                const int slot = ch * 4 + g4;
                ah[ch] = *(const short8*)(buf +        r * 128 + ((slot ^ rk) << 4));
                al[ch] = *(const short8*)(buf + 8192 + r * 128 + ((slot ^ rk) << 4));
            }
            f32x4 acc[NM];
#pragma unroll
            for (int m = 0; m < NM; ++m) {
                f32x4 a = {bias[m], bias[m], bias[m], bias[m]};
#pragma unroll
                for (int ch = 0; ch < 2; ++ch) {
                    // split precision: xh*Wh + xh*Wl + xl*Wh (xl*Wl dropped)
                    a = __builtin_amdgcn_mfma_f32_16x16x32_bf16(ah[ch], wh[m][ch], a, 0, 0, 0);
                    a = __builtin_amdgcn_mfma_f32_16x16x32_bf16(ah[ch], wl[m][ch], a, 0, 0, 0);
                    a = __builtin_amdgcn_mfma_f32_16x16x32_bf16(al[ch], wh[m][ch], a, 0, 0, 0);
                }
                acc[m] = a;
            }
            // fold over m; D: col(lane&15)=o-local, row(g4*4+rr)=pixel-local
            f32x4 v;
#pragma unroll
            for (int rr = 0; rr < 4; ++rr) {
                v[rr] = fmaxf(acc[0][rr] - qv, 0.f) + fmaxf(acc[1][rr] - qv, 0.f)
                      + fmaxf(acc[2][rr] - qv, 0.f) + fmaxf(acc[3][rr] - qv, 0.f);
            }
            *(f32x4*)(outw + it * 64 + ps * 16 + g4 * 4) = v;   // 4 consecutive pixels
        }
        // no second barrier: next iter writes the other buffer; reuse of this
        // buffer (it+2) is ordered by barrier(it+1), which every wave reaches
        // only after finishing this MFMA phase.
    }
}

extern "C" void kernel_launch(void* const* d_in, const int* in_sizes, int n_in,
                              void* d_out, int out_size, void* d_ws, size_t ws_size,
                              hipStream_t stream) {
    const float* x     = (const float*)d_in[0];
    const float* Wg    = (const float*)d_in[1];
    const float* q     = (const float*)d_in[2];
    const float* gamma = (const float*)d_in[3];
    const float* beta  = (const float*)d_in[4];
    float* out = (float*)d_out;

    dnm_fused<<<dim3(2304), dim3(256), 0, stream>>>(x, Wg, q, gamma, beta, out);
}